// Round 1
// 397.605 us; speedup vs baseline: 1.0315x; 1.0315x over previous
//
#include <hip/hip_runtime.h>
#include <stdint.h>

// Problem constants (reference: M,K,N = 8192,4096,4096)
#define GM 8192
#define GK 4096
#define GN 4096

typedef int v4i __attribute__((ext_vector_type(4)));

__device__ __forceinline__ void async_load16(const void* gptr, void* lptr) {
  __builtin_amdgcn_global_load_lds(
      (const __attribute__((address_space(1))) void*)gptr,
      (__attribute__((address_space(3))) void*)lptr,
      16 /*bytes*/, 0 /*offset*/, 0 /*aux*/);
}

// ---------------- Kernel 1: fused prep (unchanged) ----------------
#define TBLK ((GN / 64) * (GK / 64))      // 4096 transpose blocks
#define QBLK (GM * GK / 4 / 256)          // 32768 quant blocks

__global__ __launch_bounds__(256) void prep_kernel(
    const float* __restrict__ x, int8_t* __restrict__ qx,
    const float* __restrict__ scale_p, const float* __restrict__ off_p,
    const int* __restrict__ B, int8_t* __restrict__ Bt) {
  __shared__ int tile32[64][65];
  const int b = blockIdx.x;
  const int t = threadIdx.x;
  if (b < TBLK) {
    const int n0 = (b & 63) * 64;
    const int k0 = (b >> 6) * 64;
#pragma unroll
    for (int r = 0; r < 4; ++r) {
      const int kl = r * 16 + (t >> 4);
      const int nl = (t & 15) * 4;
      const int4 v = *(const int4*)(B + (size_t)(k0 + kl) * GN + n0 + nl);
      *(int4*)&tile32[kl][nl] = v;
    }
    __syncthreads();
    const int nl = t >> 2;
    const int kc = (t & 3) * 16;
    v4i out;
#pragma unroll
    for (int w = 0; w < 4; ++w) {
      int p = 0;
#pragma unroll
      for (int j = 0; j < 4; ++j)
        p |= (tile32[kc + w * 4 + j][nl] & 0xff) << (8 * j);
      out[w] = p;
    }
    *(v4i*)(Bt + (size_t)(n0 + nl) * GK + k0 + kc) = out;
  } else {
    const int i = (b - TBLK) * 256 + t;
    const float s = scale_p[0], o = off_p[0];
    const float4 f = ((const float4*)x)[i];
    float a0 = fminf(fmaxf(rintf(f.x * s + o), -128.f), 127.f);
    float b0 = fminf(fmaxf(rintf(f.y * s + o), -128.f), 127.f);
    float c0 = fminf(fmaxf(rintf(f.z * s + o), -128.f), 127.f);
    float d0 = fminf(fmaxf(rintf(f.w * s + o), -128.f), 127.f);
    int packed = (((int)a0) & 0xff) | ((((int)b0) & 0xff) << 8) |
                 ((((int)c0) & 0xff) << 16) | ((((int)d0) & 0xff) << 24);
    ((int*)qx)[i] = packed;
  }
}

// ---------------- Kernel 2: int8 GEMM, 256x256 tile, BK=128, 8 waves,
// 4-phase-per-K-tile pipelined schedule (8-phase template, i8 port).
//
// Geometry: 512 thr = 8 waves (2M x 4N), wave tile 128x64 = 8x4 frags of
// 16x16, mfma_i32_16x16x64_i8 (K split in 2 ksteps of 64 per BK=128).
// LDS: [2 dbuf][2 half][128 rows][128 B] for A and B = 128 KiB.
// T2 swizzle: LDS 16B-granule g is stored at g ^ (row&7); applied on the
// ds_read address AND inverted on the global source of global_load_lds
// (linear LDS dest). row&7 == fr&7 for all fragment rows -> two per-lane
// constants sw0/sw1.
// T3+T4: stage stream = one 16KB half-tile per phase, half index h staged
// at global phase h-6; boundary wait vmcnt(4) (2 half-tiles in flight).
// Half order per tile T: {4T+0:A-lo, 4T+1:A-hi, 4T+2:B-lo, 4T+3:B-hi}.
// Safety: a region's ds_reads are drained by that phase's lgkmcnt(0)
// (all waves) + barrier before any overwriting stage issues.
#define NT (GK / 128)  // 32 K-tiles

__global__ __launch_bounds__(512, 2) void gemm_i8_kernel(
    const int8_t* __restrict__ A, const int8_t* __restrict__ Bt,
    const int* __restrict__ bias, const float* __restrict__ deq,
    float* __restrict__ C) {
  __shared__ __align__(16) int8_t Al[2][2][128 * 128];  // 64 KB
  __shared__ __align__(16) int8_t Bl[2][2][128 * 128];  // 64 KB

  const int t = threadIdx.x;
  const int lane = t & 63;
  const int wid = t >> 6;

  // T1: XCD-aware swizzle, grid = 512 = 64/XCD (bijective, 512%8==0)
  const int bid = blockIdx.x;
  const int swz = (bid & 7) * 64 + (bid >> 3);
  const int m0 = (swz >> 4) * 256;  // 32 M-blocks
  const int n0 = (swz & 15) * 256;  // 16 N-blocks

  const int ahalf = wid >> 2;         // wave's A half (M)
  const int bhalf = (wid & 3) >> 1;   // wave's B half (N)
  const int bloc = (wid & 1) * 64;    // row offset inside B half
  const int wm = ahalf * 128;
  const int wn = (wid & 3) * 64;

  const int fr = lane & 15;
  const int kq = lane >> 4;
  const int sw0 = ((kq) ^ (fr & 7)) * 16;      // kstep 0 granule swizzle
  const int sw1 = ((4 + kq) ^ (fr & 7)) * 16;  // kstep 1

  // staging precompute: thread t covers row srow (+64 on sweep 1),
  // physical granule t&7 -> logical granule lg (same both sweeps).
  const int srow = t >> 3;                        // 0..63
  const int lg16 = (((t & 7) ^ (srow & 7)) * 16); // swizzled source col
  const int ldst = t * 16;                        // linear LDS dest

  v4i acc[8][4];
  const v4i vz = {0, 0, 0, 0};
#pragma unroll
  for (int m = 0; m < 8; ++m)
#pragma unroll
    for (int n = 0; n < 4; ++n) acc[m][n] = vz;

#define STAGE(hh)                                                         \
  do {                                                                    \
    const int h_ = (hh);                                                  \
    const int T_ = h_ >> 2, c_ = h_ & 3, b_ = T_ & 1;                     \
    const size_t ko_ = (size_t)T_ * 128 + lg16;                           \
    if (c_ < 2) {                                                         \
      const int8_t* s_ = A + (size_t)(m0 + c_ * 128 + srow) * GK + ko_;   \
      int8_t* d_ = &Al[b_][c_][0] + ldst;                                 \
      async_load16(s_, d_);                                               \
      async_load16(s_ + (size_t)64 * GK, d_ + 8192);                      \
    } else {                                                              \
      const int8_t* s_ =                                                  \
          Bt + (size_t)(n0 + (c_ - 2) * 128 + srow) * GK + ko_;           \
      int8_t* d_ = &Bl[b_][c_ - 2][0] + ldst;                             \
      async_load16(s_, d_);                                               \
      async_load16(s_ + (size_t)64 * GK, d_ + 8192);                      \
    }                                                                     \
  } while (0)

#define READ_A(dst, swz_)                                                 \
  do {                                                                    \
    const int8_t* p_ = &Al[buf][ahalf][0] + fr * 128 + (swz_);            \
    _Pragma("unroll") for (int i_ = 0; i_ < 8; ++i_)                      \
        dst[i_] = *(const v4i*)(p_ + i_ * 2048);                          \
  } while (0)

#define READ_B(dst, swz_)                                                 \
  do {                                                                    \
    const int8_t* p_ = &Bl[buf][bhalf][0] + (bloc + fr) * 128 + (swz_);   \
    _Pragma("unroll") for (int i_ = 0; i_ < 4; ++i_)                      \
        dst[i_] = *(const v4i*)(p_ + i_ * 2048);                          \
  } while (0)

#define QUAD(AF, BF, MB)                                                  \
  do {                                                                    \
    _Pragma("unroll") for (int mi_ = 0; mi_ < 4; ++mi_) {                 \
      _Pragma("unroll") for (int ni_ = 0; ni_ < 4; ++ni_) {               \
        acc[(MB) + mi_][ni_] = __builtin_amdgcn_mfma_i32_16x16x64_i8(     \
            AF[(MB) + mi_], BF[ni_], acc[(MB) + mi_][ni_], 0, 0, 0);      \
      }                                                                   \
    }                                                                     \
  } while (0)

#define LGKM0 asm volatile("s_waitcnt lgkmcnt(0)" ::: "memory")
#define VMC4 asm volatile("s_waitcnt vmcnt(4)" ::: "memory")
#define VMC0 asm volatile("s_waitcnt vmcnt(0)" ::: "memory")
#define BAR __builtin_amdgcn_s_barrier()

  v4i a0[8], a1[8], b0[4], b1[4];

  // Prologue: halves 0..5 (tile 0 A+B, tile 1 A) = 12 loads; allow the
  // newest 2 halves (4 loads) in flight.
  STAGE(0); STAGE(1); STAGE(2); STAGE(3); STAGE(4); STAGE(5);
  VMC4;
  BAR;

#pragma unroll 2
  for (int kt = 0; kt < NT - 2; ++kt) {  // kt = 0..29, stages always valid
    const int buf = kt & 1;
    const int hb = 4 * kt + 6;
    // P0: read ks0 frags; stage B-lo of kt+1
    READ_A(a0, sw0);
    READ_B(b0, sw0);
    STAGE(hb);
    BAR;
    LGKM0;
    __builtin_amdgcn_s_setprio(1);
    QUAD(a0, b0, 0);
    __builtin_amdgcn_s_setprio(0);
    BAR;
    // P1: read A ks1; stage B-hi of kt+1
    READ_A(a1, sw1);
    STAGE(hb + 1);
    BAR;
    LGKM0;  // drains a1 so P2's A-region stage is race-free
    __builtin_amdgcn_s_setprio(1);
    QUAD(a0, b0, 4);
    __builtin_amdgcn_s_setprio(0);
    BAR;
    // P2: read B ks1; stage A-lo of kt+2 (A reads fully drained at P1)
    READ_B(b1, sw1);
    STAGE(hb + 2);
    BAR;
    LGKM0;
    __builtin_amdgcn_s_setprio(1);
    QUAD(a1, b1, 0);
    __builtin_amdgcn_s_setprio(0);
    BAR;
    // P3: stage A-hi of kt+2; boundary wait vmcnt(4) (A of kt+2 in flight)
    STAGE(hb + 3);
    __builtin_amdgcn_s_setprio(1);
    QUAD(a1, b1, 4);
    __builtin_amdgcn_s_setprio(0);
    VMC4;
    BAR;
  }
  // kt = 30 (buf 0): only B of tile 31 left to stage; full drain at end.
  {
    const int buf = 0;
    READ_A(a0, sw0);
    READ_B(b0, sw0);
    STAGE(126);
    BAR;
    LGKM0;
    __builtin_amdgcn_s_setprio(1);
    QUAD(a0, b0, 0);
    __builtin_amdgcn_s_setprio(0);
    BAR;
    READ_A(a1, sw1);
    STAGE(127);
    BAR;
    LGKM0;
    __builtin_amdgcn_s_setprio(1);
    QUAD(a0, b0, 4);
    __builtin_amdgcn_s_setprio(0);
    BAR;
    READ_B(b1, sw1);
    BAR;
    LGKM0;
    __builtin_amdgcn_s_setprio(1);
    QUAD(a1, b1, 0);
    __builtin_amdgcn_s_setprio(0);
    BAR;
    __builtin_amdgcn_s_setprio(1);
    QUAD(a1, b1, 4);
    __builtin_amdgcn_s_setprio(0);
    VMC0;
    BAR;
  }
  // kt = 31 (buf 1): no stages, no barriers needed (compiler tracks deps).
  {
    const int buf = 1;
    READ_A(a0, sw0);
    READ_B(b0, sw0);
    READ_A(a1, sw1);
    READ_B(b1, sw1);
    QUAD(a0, b0, 0);
    QUAD(a0, b0, 4);
    QUAD(a1, b1, 0);
    QUAD(a1, b1, 4);
  }

  // Epilogue. C/D layout: col = lane&15, row = (lane>>4)*4 + reg (m89).
  const int col = lane & 15;
  const int rq = (lane >> 4) * 4;
#pragma unroll
  for (int n = 0; n < 4; ++n) {
    const int gc = n0 + wn + n * 16 + col;
    const float d = deq[gc];
    const int bs = bias[gc];
#pragma unroll
    for (int m = 0; m < 8; ++m) {
      const int gr = m0 + wm + m * 16 + rq;
#pragma unroll
      for (int r = 0; r < 4; ++r)
        C[(size_t)(gr + r) * GN + gc] = (float)(acc[m][n][r] + bs) * d;
    }
  }
#undef STAGE
#undef READ_A
#undef READ_B
#undef QUAD
#undef LGKM0
#undef VMC4
#undef VMC0
#undef BAR
}

extern "C" void kernel_launch(void* const* d_in, const int* in_sizes, int n_in,
                              void* d_out, int out_size, void* d_ws, size_t ws_size,
                              hipStream_t stream) {
  const float* x = (const float*)d_in[0];
  const int* qw = (const int*)d_in[1];        // int8 in reference -> int32 on device
  const float* act_scale = (const float*)d_in[2];
  const float* act_offset = (const float*)d_in[3];
  const float* deq = (const float*)d_in[4];
  const int* bias = (const int*)d_in[5];
  float* out = (float*)d_out;

  // Workspace: qx [M*K int8] then Bt [N*K int8]  (48 MB total)
  int8_t* qx = (int8_t*)d_ws;
  int8_t* Bt = (int8_t*)d_ws + (size_t)GM * GK;

  prep_kernel<<<TBLK + QBLK, 256, 0, stream>>>(x, qx, act_scale, act_offset, qw, Bt);
  gemm_i8_kernel<<<dim3((GM / 256) * (GN / 256)), 512, 0, stream>>>(qx, Bt, bias, deq, out);
}

// Round 2
// 390.620 us; speedup vs baseline: 1.0499x; 1.0179x over previous
//
#include <hip/hip_runtime.h>
#include <stdint.h>

// Problem constants (reference: M,K,N = 8192,4096,4096)
#define GM 8192
#define GK 4096
#define GN 4096

typedef int v4i __attribute__((ext_vector_type(4)));

__device__ __forceinline__ void async_load16(const void* gptr, void* lptr) {
  __builtin_amdgcn_global_load_lds(
      (const __attribute__((address_space(1))) void*)gptr,
      (__attribute__((address_space(3))) void*)lptr,
      16 /*bytes*/, 0 /*offset*/, 0 /*aux*/);
}

// ---------------- Kernel 1: fused prep (unchanged) ----------------
#define TBLK ((GN / 64) * (GK / 64))      // 4096 transpose blocks
#define QBLK (GM * GK / 4 / 256)          // 32768 quant blocks

__global__ __launch_bounds__(256) void prep_kernel(
    const float* __restrict__ x, int8_t* __restrict__ qx,
    const float* __restrict__ scale_p, const float* __restrict__ off_p,
    const int* __restrict__ B, int8_t* __restrict__ Bt) {
  __shared__ int tile32[64][65];
  const int b = blockIdx.x;
  const int t = threadIdx.x;
  if (b < TBLK) {
    const int n0 = (b & 63) * 64;
    const int k0 = (b >> 6) * 64;
#pragma unroll
    for (int r = 0; r < 4; ++r) {
      const int kl = r * 16 + (t >> 4);
      const int nl = (t & 15) * 4;
      const int4 v = *(const int4*)(B + (size_t)(k0 + kl) * GN + n0 + nl);
      *(int4*)&tile32[kl][nl] = v;
    }
    __syncthreads();
    const int nl = t >> 2;
    const int kc = (t & 3) * 16;
    v4i out;
#pragma unroll
    for (int w = 0; w < 4; ++w) {
      int p = 0;
#pragma unroll
      for (int j = 0; j < 4; ++j)
        p |= (tile32[kc + w * 4 + j][nl] & 0xff) << (8 * j);
      out[w] = p;
    }
    *(v4i*)(Bt + (size_t)(n0 + nl) * GK + k0 + kc) = out;
  } else {
    const int i = (b - TBLK) * 256 + t;
    const float s = scale_p[0], o = off_p[0];
    const float4 f = ((const float4*)x)[i];
    float a0 = fminf(fmaxf(rintf(f.x * s + o), -128.f), 127.f);
    float b0 = fminf(fmaxf(rintf(f.y * s + o), -128.f), 127.f);
    float c0 = fminf(fmaxf(rintf(f.z * s + o), -128.f), 127.f);
    float d0 = fminf(fmaxf(rintf(f.w * s + o), -128.f), 127.f);
    int packed = (((int)a0) & 0xff) | ((((int)b0) & 0xff) << 8) |
                 ((((int)c0) & 0xff) << 16) | ((((int)d0) & 0xff) << 24);
    ((int*)qx)[i] = packed;
  }
}

// ---------------- Kernel 2: int8 GEMM, 256x256 tile, BK=128, 8 waves.
// Round-2 schedule: 2 MFMA clusters per K-tile, cross-phase register
// prefetch, ONE barrier per K-tile.
//
// Rationale (round-1 post-mortem): i8 K=64 fragments halve LDS bytes per
// MFMA-cycle vs the bf16 template, so the fine 4-phase/8-barrier schedule
// was pure overhead (measured 5616 cyc/kt vs 2611 cyc MFMA-pipe need).
// New steady state per kt (buf = kt&1):
//   P0: read a1,b1(kt)[12 ds_read_b128]; STAGE tile kt+1 -> buf^1 [8 DMA];
//       MFMA(a0,b0)[32];
//       s_waitcnt lgkmcnt(0) vmcnt(0); s_barrier      // the ONLY barrier
//   P1: read a0,b0(kt+1) from buf^1 (published by the barrier);
//       MFMA(a1,b1)[32]
// Every 12-read batch is issued one full MFMA cluster (~1300 cyc) before
// consumption -> LDS latency fully hidden. vmcnt(0) waits own stages
// issued ~1300+ cyc earlier (covers 900-cyc HBM latency) -> ~free.
// Strict race-freedom: all reads of buf[kt] drain at the lgkmcnt(0)
// before BAR(kt); the conflicting stage (tile kt+2 -> buf[kt]) issues
// only after BAR(kt). Reads of buf^1 (kt+1 frags) issue only after the
// publishing barrier (each wave vmcnt(0)-drained its own DMA before it).
#define NT (GK / 128)  // 32 K-tiles

__global__ __launch_bounds__(512, 2) void gemm_i8_kernel(
    const int8_t* __restrict__ A, const int8_t* __restrict__ Bt,
    const int* __restrict__ bias, const float* __restrict__ deq,
    float* __restrict__ C) {
  __shared__ __align__(16) int8_t Al[2][2][128 * 128];  // 64 KB
  __shared__ __align__(16) int8_t Bl[2][2][128 * 128];  // 64 KB

  const int t = threadIdx.x;
  const int lane = t & 63;
  const int wid = t >> 6;

  // T1: XCD-aware swizzle, grid = 512 (bijective, 512%8==0)
  const int bid = blockIdx.x;
  const int swz = (bid & 7) * 64 + (bid >> 3);
  const int m0 = (swz >> 4) * 256;  // 32 M-blocks
  const int n0 = (swz & 15) * 256;  // 16 N-blocks

  const int ahalf = wid >> 2;        // wave's A half (M)
  const int bhalf = (wid & 3) >> 1;  // wave's B half (N)
  const int bloc = (wid & 1) * 64;   // row offset inside B half
  const int wm = ahalf * 128;
  const int wn = (wid & 3) * 64;

  // T2 swizzle constants (same mapping as round 1, verified absmax 0.0):
  // LDS granule g of row r stored at g ^ (r&7); fragment rows have
  // row&7 == fr&7 -> per-lane constants.
  const int fr = lane & 15;
  const int kq = lane >> 4;
  const int sw0 = ((kq) ^ (fr & 7)) * 16;      // kstep 0
  const int sw1 = ((4 + kq) ^ (fr & 7)) * 16;  // kstep 1

  // staging: thread t covers row srow of each 64-row sweep; source col
  // pre-swizzled so the linear LDS dest (t*16) holds the swizzled layout.
  const int srow = t >> 3;                         // 0..63
  const int lg16 = (((t & 7) ^ (srow & 7)) * 16);  // swizzled source col
  const int ldst = t * 16;                         // linear LDS dest

  v4i acc[8][4];
  const v4i vz = {0, 0, 0, 0};
#pragma unroll
  for (int m = 0; m < 8; ++m)
#pragma unroll
    for (int n = 0; n < 4; ++n) acc[m][n] = vz;

// Stage ALL of tile T (A 256 rows + B 256 rows, BK=128) into buf (T&1).
// 8 global_load_lds per thread; LDS dest linear (wave-uniform + lane*16).
#define STAGE_TILE(T)                                                  \
  do {                                                                 \
    const int T_ = (T), b_ = T_ & 1;                                   \
    const size_t ko_ = (size_t)T_ * 128 + lg16;                        \
    const int8_t* sa_ = A + (size_t)(m0 + srow) * GK + ko_;            \
    int8_t* da_ = &Al[b_][0][0] + ldst;                                \
    async_load16(sa_, da_);                                            \
    async_load16(sa_ + (size_t)64 * GK, da_ + 8192);                   \
    async_load16(sa_ + (size_t)128 * GK, da_ + 16384);                 \
    async_load16(sa_ + (size_t)192 * GK, da_ + 24576);                 \
    const int8_t* sb_ = Bt + (size_t)(n0 + srow) * GK + ko_;           \
    int8_t* db_ = &Bl[b_][0][0] + ldst;                                \
    async_load16(sb_, db_);                                            \
    async_load16(sb_ + (size_t)64 * GK, db_ + 8192);                   \
    async_load16(sb_ + (size_t)128 * GK, db_ + 16384);                 \
    async_load16(sb_ + (size_t)192 * GK, db_ + 24576);                 \
  } while (0)

#define READ_A(dst, bb, swz_)                                          \
  do {                                                                 \
    const int8_t* p_ = &Al[bb][ahalf][0] + fr * 128 + (swz_);          \
    _Pragma("unroll") for (int i_ = 0; i_ < 8; ++i_)                   \
        dst[i_] = *(const v4i*)(p_ + i_ * 2048);                       \
  } while (0)

#define READ_B(dst, bb, swz_)                                          \
  do {                                                                 \
    const int8_t* p_ = &Bl[bb][bhalf][0] + (bloc + fr) * 128 + (swz_); \
    _Pragma("unroll") for (int i_ = 0; i_ < 4; ++i_)                   \
        dst[i_] = *(const v4i*)(p_ + i_ * 2048);                       \
  } while (0)

#define QUAD(AF, BF, MB)                                               \
  do {                                                                 \
    _Pragma("unroll") for (int mi_ = 0; mi_ < 4; ++mi_) {              \
      _Pragma("unroll") for (int ni_ = 0; ni_ < 4; ++ni_) {            \
        acc[(MB) + mi_][ni_] = __builtin_amdgcn_mfma_i32_16x16x64_i8(  \
            AF[(MB) + mi_], BF[ni_], acc[(MB) + mi_][ni_], 0, 0, 0);   \
      }                                                                \
    }                                                                  \
  } while (0)

  v4i a0[8], b0[4], a1[8], b1[4];

  // Prologue: tile 0 resident + published; a0,b0(0) in regs.
  STAGE_TILE(0);
  asm volatile("s_waitcnt vmcnt(0)\ns_barrier" ::: "memory");
  READ_A(a0, 0, sw0);
  READ_B(b0, 0, sw0);

#pragma unroll 2
  for (int kt = 0; kt < NT - 1; ++kt) {
    const int buf = kt & 1;
    // ---- P0: prefetch kstep-1 frags; stage next tile; compute kstep 0.
    READ_A(a1, buf, sw1);
    READ_B(b1, buf, sw1);
    STAGE_TILE(kt + 1);
    __builtin_amdgcn_s_setprio(1);
    QUAD(a0, b0, 0);
    QUAD(a0, b0, 4);
    __builtin_amdgcn_s_setprio(0);
    // Single sync point: drain own ds_reads (race-freedom for the stage
    // into buf[kt] issued next iteration) + own DMA (publish tile kt+1).
    asm volatile("s_waitcnt lgkmcnt(0) vmcnt(0)\n\ts_barrier" ::: "memory");
    // ---- P1: prefetch next tile's kstep-0 frags; compute kstep 1.
    READ_A(a0, buf ^ 1, sw0);
    READ_B(b0, buf ^ 1, sw0);
    __builtin_amdgcn_s_setprio(1);
    QUAD(a1, b1, 0);
    QUAD(a1, b1, 4);
    __builtin_amdgcn_s_setprio(0);
  }
  // ---- Tail: kt = NT-1 (buf 1), no staging, no barriers.
  {
    const int buf = (NT - 1) & 1;
    READ_A(a1, buf, sw1);
    READ_B(b1, buf, sw1);
    QUAD(a0, b0, 0);
    QUAD(a0, b0, 4);
    QUAD(a1, b1, 0);
    QUAD(a1, b1, 4);
  }

  // Epilogue. C/D layout: col = lane&15, row = (lane>>4)*4 + reg (m89).
  const int col = lane & 15;
  const int rq = (lane >> 4) * 4;
#pragma unroll
  for (int n = 0; n < 4; ++n) {
    const int gc = n0 + wn + n * 16 + col;
    const float d = deq[gc];
    const int bs = bias[gc];
#pragma unroll
    for (int m = 0; m < 8; ++m) {
      const int gr = m0 + wm + m * 16 + rq;
#pragma unroll
      for (int r = 0; r < 4; ++r)
        C[(size_t)(gr + r) * GN + gc] = (float)(acc[m][n][r] + bs) * d;
    }
  }
#undef STAGE_TILE
#undef READ_A
#undef READ_B
#undef QUAD
}

extern "C" void kernel_launch(void* const* d_in, const int* in_sizes, int n_in,
                              void* d_out, int out_size, void* d_ws, size_t ws_size,
                              hipStream_t stream) {
  const float* x = (const float*)d_in[0];
  const int* qw = (const int*)d_in[1];        // int8 in reference -> int32 on device
  const float* act_scale = (const float*)d_in[2];
  const float* act_offset = (const float*)d_in[3];
  const float* deq = (const float*)d_in[4];
  const int* bias = (const int*)d_in[5];
  float* out = (float*)d_out;

  // Workspace: qx [M*K int8] then Bt [N*K int8]  (48 MB total)
  int8_t* qx = (int8_t*)d_ws;
  int8_t* Bt = (int8_t*)d_ws + (size_t)GM * GK;

  prep_kernel<<<TBLK + QBLK, 256, 0, stream>>>(x, qx, act_scale, act_offset, qw, Bt);
  gemm_i8_kernel<<<dim3((GM / 256) * (GN / 256)), 512, 0, stream>>>(qx, Bt, bias, deq, out);
}